// Round 3
// baseline (148.411 us; speedup 1.0000x reference)
//
#include <hip/hip_runtime.h>
#include <hip/hip_bf16.h>
#include <hip/hip_fp8.h>

#define NNODE 50000
#define MTOT  100000   // 2*NNODE rows
#define NF    256
#define KNB   10

typedef unsigned short u16;
typedef float f32x4 __attribute__((ext_vector_type(4)));
typedef short bf16x8 __attribute__((ext_vector_type(8)));

__device__ __forceinline__ u16 f2bf(float f) {
    unsigned u = __builtin_bit_cast(unsigned, f);
    unsigned r = (u + 0x7fffu + ((u >> 16) & 1u)) >> 16;
    return (u16)r;
}
__device__ __forceinline__ unsigned char f2f8(float f) {
    return (unsigned char)__hip_fp8_e4m3(f).__x;
}
__device__ __forceinline__ float f8tof(unsigned char b) {
    __hip_fp8_e4m3 h;
    h.__x = (__hip_fp8_storage_t)b;
    return (float)h;
}
__device__ __forceinline__ void gload_lds16(const void* g, void* l) {
    __builtin_amdgcn_global_load_lds(
        (const __attribute__((address_space(1))) unsigned int*)g,
        (__attribute__((address_space(3))) unsigned int*)l, 16, 0, 0);
}

// ---- kernel 1: W^T cast: WT[n][k] = bf16( k<256 ? Wr[k][n] : Wnr[k-256][n] )
__global__ __launch_bounds__(256) void cast_w(const float* __restrict__ Wr,
                                              const float* __restrict__ Wnr,
                                              u16* __restrict__ WT) {
    int id = blockIdx.x * 256 + threadIdx.x;   // 131072 total
    int n = id >> 9;        // 0..255
    int k = id & 511;       // 0..511
    float v = (k < 256) ? Wr[(size_t)k * 256 + n] : Wnr[(size_t)(k - 256) * 256 + n];
    WT[(size_t)n * 512 + k] = f2bf(v);
}

// ---- kernel 2: cast Z f32 -> bf16 Zleft[m][256] AND fp8 Z8[m][256] (gather source)
__global__ __launch_bounds__(256) void cast_z(const float* __restrict__ Z1,
                                              const float* __restrict__ Z2,
                                              u16* __restrict__ Zleft,
                                              unsigned char* __restrict__ Z8) {
    unsigned id = blockIdx.x * 256 + threadIdx.x;  // 3,200,000 total (8 elems each)
    int m = id >> 5;
    int d = (id & 31) << 3;
    const float* src = (m < NNODE) ? (Z1 + (size_t)m * 256 + d)
                                   : (Z2 + (size_t)(m - NNODE) * 256 + d);
    float4 a = *(const float4*)src;
    float4 b = *(const float4*)(src + 4);
    uint4 o;
    o.x = (unsigned)f2bf(a.x) | ((unsigned)f2bf(a.y) << 16);
    o.y = (unsigned)f2bf(a.z) | ((unsigned)f2bf(a.w) << 16);
    o.z = (unsigned)f2bf(b.x) | ((unsigned)f2bf(b.y) << 16);
    o.w = (unsigned)f2bf(b.z) | ((unsigned)f2bf(b.w) << 16);
    *(uint4*)(Zleft + (size_t)m * 256 + d) = o;
    uint2 o8;
    o8.x = (unsigned)f2f8(a.x) | ((unsigned)f2f8(a.y) << 8) |
           ((unsigned)f2f8(a.z) << 16) | ((unsigned)f2f8(a.w) << 24);
    o8.y = (unsigned)f2f8(b.x) | ((unsigned)f2f8(b.y) << 8) |
           ((unsigned)f2f8(b.z) << 16) | ((unsigned)f2f8(b.w) << 24);
    *(uint2*)(Z8 + (size_t)m * 256 + d) = o8;
}

// ---- kernel 3: FUSED gather + GEMM.  out = relu([Zleft | avg(Z8[nb])] @ WT^T)
// M-tile=64, N=256 full, BK=64. 256 thr = 4 waves (1M x 4N), wave = 64x64 = 4x4 frags.
// LDS: sA 8KB + sB 32KB + sZ 32KB = 72KB -> 2 blocks/CU.
__global__ __launch_bounds__(256, 2) void gemm_fused(const u16* __restrict__ A,           // [MTOT][256] bf16
                                                     const unsigned char* __restrict__ Z8,// [MTOT][256] fp8
                                                     const u16* __restrict__ BT,          // [256][512] bf16
                                                     const int* __restrict__ n1,
                                                     const int* __restrict__ n2,
                                                     float* __restrict__ C) {
    __shared__ u16 sA[64 * 64];     // left-half A K-tile
    __shared__ u16 sB[256 * 64];    // B K-tile (all 256 out-cols)
    __shared__ u16 sZ[64 * 256];    // gathered Zavg, XOR-swizzled 16B granules
    const int m0 = blockIdx.x * 64;
    const int t = threadIdx.x;
    const int lane = t & 63;
    const int w = t >> 6;           // wave 0..3 -> out-col group w*64

    // ---- gather prologue: wave w averages rows w*16 .. w*16+15 into sZ
    {
        const unsigned char* zb = Z8 + lane * 4;
        for (int rr = 0; rr < 16; ++rr) {
            int r = w * 16 + rr;
            int g = m0 + r;
            if (g >= MTOT) g = MTOT - 1;       // padded rows: duplicate last (store-guarded)
            int p = (g >= NNODE);
            int i = g - p * NNODE;
            const int* nb = (p ? n2 : n1) + (size_t)i * KNB;
            float a0 = 0.f, a1 = 0.f, a2 = 0.f, a3 = 0.f;
            int cnt = 0;
            #pragma unroll
            for (int k = 0; k < KNB; ++k) {
                int idx = nb[k];
                int valid = (idx > -1);
                cnt += valid;
                uchar4 v = *(const uchar4*)(zb + (size_t)(p * NNODE + (valid ? idx : 0)) * 256);
                float mm = (float)valid;
                a0 += mm * f8tof(v.x); a1 += mm * f8tof(v.y);
                a2 += mm * f8tof(v.z); a3 += mm * f8tof(v.w);
            }
            float s = 1.0f / (float)(cnt > 0 ? cnt : 1);
            ushort4 o;
            o.x = f2bf(a0 * s); o.y = f2bf(a1 * s); o.z = f2bf(a2 * s); o.w = f2bf(a3 * s);
            // swizzled write: 16B granule (lane>>1) XOR (row&7), half-granule (lane&1)
            int byteoff = r * 512 + ((((lane >> 1) ^ (r & 7)) << 4) | ((lane & 1) << 3));
            *(ushort4*)((char*)sZ + byteoff) = o;
        }
    }
    // sZ reads happen only in the right-half loop, after several __syncthreads.

    f32x4 acc[4][4] = {};

    // ---- left half: kt = 0..255, A staged from global bf16
    for (int kt = 0; kt < 256; kt += 64) {
        #pragma unroll
        for (int rp = 0; rp < 2; ++rp) {
            int c = rp * 256 + t;          // 512 chunks of 16B
            int row = c >> 3, kc = c & 7;
            int grow = m0 + row;
            if (grow >= MTOT) grow = MTOT - 1;
            gload_lds16(A + (size_t)grow * 256 + kt + kc * 8, &sA[c * 8]);
        }
        #pragma unroll
        for (int rp = 0; rp < 8; ++rp) {
            int c = rp * 256 + t;          // 2048 chunks of 16B
            int col = c >> 3, kc = c & 7;
            gload_lds16(BT + (size_t)col * 512 + kt + kc * 8, &sB[c * 8]);
        }
        asm volatile("s_waitcnt vmcnt(0)");
        __syncthreads();
        #pragma unroll
        for (int kk = 0; kk < 64; kk += 32) {
            int kq = kk + ((lane >> 4) << 3);
            bf16x8 af[4], bfr[4];
            #pragma unroll
            for (int i = 0; i < 4; ++i) {
                int row = i * 16 + (lane & 15);
                af[i] = *(const bf16x8*)&sA[row * 64 + kq];
            }
            #pragma unroll
            for (int j = 0; j < 4; ++j) {
                int col = w * 64 + j * 16 + (lane & 15);
                bfr[j] = *(const bf16x8*)&sB[col * 64 + kq];
            }
            #pragma unroll
            for (int i = 0; i < 4; ++i)
                #pragma unroll
                for (int j = 0; j < 4; ++j)
                    acc[i][j] = __builtin_amdgcn_mfma_f32_16x16x32_bf16(af[i], bfr[j], acc[i][j], 0, 0, 0);
        }
        __syncthreads();
    }

    // ---- right half: kt = 256..511, A frags from sZ (swizzled), only B staged
    for (int kt = 256; kt < 512; kt += 64) {
        #pragma unroll
        for (int rp = 0; rp < 8; ++rp) {
            int c = rp * 256 + t;
            int col = c >> 3, kc = c & 7;
            gload_lds16(BT + (size_t)col * 512 + kt + kc * 8, &sB[c * 8]);
        }
        asm volatile("s_waitcnt vmcnt(0)");
        __syncthreads();
        #pragma unroll
        for (int kk = 0; kk < 64; kk += 32) {
            int kq = kk + ((lane >> 4) << 3);
            bf16x8 af[4], bfr[4];
            #pragma unroll
            for (int i = 0; i < 4; ++i) {
                int row = i * 16 + (lane & 15);
                int kcol = (kt - 256) + kq;    // 0..255, 8-aligned
                int byteoff = row * 512 + ((((kcol >> 3) ^ (row & 7)) << 4));
                af[i] = *(const bf16x8*)((const char*)sZ + byteoff);
            }
            #pragma unroll
            for (int j = 0; j < 4; ++j) {
                int col = w * 64 + j * 16 + (lane & 15);
                bfr[j] = *(const bf16x8*)&sB[col * 64 + kq];
            }
            #pragma unroll
            for (int i = 0; i < 4; ++i)
                #pragma unroll
                for (int j = 0; j < 4; ++j)
                    acc[i][j] = __builtin_amdgcn_mfma_f32_16x16x32_bf16(af[i], bfr[j], acc[i][j], 0, 0, 0);
        }
        __syncthreads();
    }

    // ---- epilogue: relu + store (C/D layout: col = lane&15, row = (lane>>4)*4 + q)
    #pragma unroll
    for (int i = 0; i < 4; ++i) {
        int rbase = m0 + i * 16 + ((lane >> 4) << 2);
        #pragma unroll
        for (int j = 0; j < 4; ++j) {
            int col = w * 64 + j * 16 + (lane & 15);
            #pragma unroll
            for (int q = 0; q < 4; ++q) {
                int row = rbase + q;
                if (row < MTOT) C[(size_t)row * NF + col] = fmaxf(acc[i][j][q], 0.f);
            }
        }
    }
}

extern "C" void kernel_launch(void* const* d_in, const int* in_sizes, int n_in,
                              void* d_out, int out_size, void* d_ws, size_t ws_size,
                              hipStream_t stream) {
    const float* Z1  = (const float*)d_in[0];
    const float* Z2  = (const float*)d_in[1];
    const float* Wr  = (const float*)d_in[2];
    const float* Wnr = (const float*)d_in[3];
    const int*   n1  = (const int*)d_in[4];
    const int*   n2  = (const int*)d_in[5];
    float* out = (float*)d_out;

    u16* WT    = (u16*)d_ws;                            // [256][512]    0.26 MB
    u16* Zleft = WT + 256 * 512;                        // [100000][256] 51.2 MB
    unsigned char* Z8 = (unsigned char*)(Zleft + (size_t)MTOT * 256);  // [100000][256] 25.6 MB
    // total ws use: 77.1 MB

    cast_w<<<512, 256, 0, stream>>>(Wr, Wnr, WT);
    cast_z<<<12500, 256, 0, stream>>>(Z1, Z2, Zleft, Z8);
    gemm_fused<<<1563, 256, 0, stream>>>(Zleft, Z8, WT, n1, n2, out);
}

// Round 4
// 140.602 us; speedup vs baseline: 1.0555x; 1.0555x over previous
//
#include <hip/hip_runtime.h>
#include <hip/hip_bf16.h>
#include <hip/hip_fp8.h>

#define NNODE 50000
#define MTOT  100000   // 2*NNODE rows
#define NF    256
#define KNB   10

typedef unsigned short u16;
typedef float f32x4 __attribute__((ext_vector_type(4)));
typedef short bf16x8 __attribute__((ext_vector_type(8)));

__device__ __forceinline__ u16 f2bf(float f) {
    unsigned u = __builtin_bit_cast(unsigned, f);
    unsigned r = (u + 0x7fffu + ((u >> 16) & 1u)) >> 16;
    return (u16)r;
}
__device__ __forceinline__ unsigned char f2f8(float f) {
    return (unsigned char)__hip_fp8_e4m3(f).__x;
}
__device__ __forceinline__ float f8tof(unsigned char b) {
    __hip_fp8_e4m3 h;
    h.__x = (__hip_fp8_storage_t)b;
    return (float)h;
}
__device__ __forceinline__ void gload_lds16(const void* g, void* l) {
    __builtin_amdgcn_global_load_lds(
        (const __attribute__((address_space(1))) unsigned int*)g,
        (__attribute__((address_space(3))) unsigned int*)l, 16, 0, 0);
}

// ---- kernel 1: W^T cast: WT[n][k] = bf16( k<256 ? Wr[k][n] : Wnr[k-256][n] )
__global__ __launch_bounds__(256) void cast_w(const float* __restrict__ Wr,
                                              const float* __restrict__ Wnr,
                                              u16* __restrict__ WT) {
    int id = blockIdx.x * 256 + threadIdx.x;   // 131072 total
    int n = id >> 9;        // 0..255
    int k = id & 511;       // 0..511
    float v = (k < 256) ? Wr[(size_t)k * 256 + n] : Wnr[(size_t)(k - 256) * 256 + n];
    WT[(size_t)n * 512 + k] = f2bf(v);
}

// ---- kernel 2: cast Z f32 -> bf16 Zleft[m][256] AND fp8 Z8[m][256] (gather source)
__global__ __launch_bounds__(256) void cast_z(const float* __restrict__ Z1,
                                              const float* __restrict__ Z2,
                                              u16* __restrict__ Zleft,
                                              unsigned char* __restrict__ Z8) {
    unsigned id = blockIdx.x * 256 + threadIdx.x;  // 3,200,000 total (8 elems each)
    int m = id >> 5;
    int d = (id & 31) << 3;
    const float* src = (m < NNODE) ? (Z1 + (size_t)m * 256 + d)
                                   : (Z2 + (size_t)(m - NNODE) * 256 + d);
    float4 a = *(const float4*)src;
    float4 b = *(const float4*)(src + 4);
    uint4 o;
    o.x = (unsigned)f2bf(a.x) | ((unsigned)f2bf(a.y) << 16);
    o.y = (unsigned)f2bf(a.z) | ((unsigned)f2bf(a.w) << 16);
    o.z = (unsigned)f2bf(b.x) | ((unsigned)f2bf(b.y) << 16);
    o.w = (unsigned)f2bf(b.z) | ((unsigned)f2bf(b.w) << 16);
    *(uint4*)(Zleft + (size_t)m * 256 + d) = o;
    uint2 o8;
    o8.x = (unsigned)f2f8(a.x) | ((unsigned)f2f8(a.y) << 8) |
           ((unsigned)f2f8(a.z) << 16) | ((unsigned)f2f8(a.w) << 24);
    o8.y = (unsigned)f2f8(b.x) | ((unsigned)f2f8(b.y) << 8) |
           ((unsigned)f2f8(b.z) << 16) | ((unsigned)f2f8(b.w) << 24);
    *(uint2*)(Z8 + (size_t)m * 256 + d) = o8;
}

// ---- staging helpers: linear LDS dest + INVERSE-swizzled global source (rule #21)
__device__ __forceinline__ void stage_tileA(const u16* __restrict__ A, u16* dst,
                                            int m0, int kt, int t) {
    #pragma unroll
    for (int rp = 0; rp < 2; ++rp) {           // 1024 granules of 16B, 2/thread
        int c = rp * 512 + t;
        int row = c >> 3, gd = c & 7;
        int gs = gd ^ (row & 7);               // inverse swizzle on source
        int grow = m0 + row;
        if (grow >= MTOT) grow = MTOT - 1;
        gload_lds16(A + (size_t)grow * 256 + kt + gs * 8, dst + c * 8);
    }
}
__device__ __forceinline__ void stage_tileB(const u16* __restrict__ BT, u16* dst,
                                            int kt, int t) {
    #pragma unroll
    for (int rp = 0; rp < 4; ++rp) {           // 2048 granules of 16B, 4/thread
        int c = rp * 512 + t;
        int col = c >> 3, gd = c & 7;
        int gs = gd ^ (col & 7);
        gload_lds16(BT + (size_t)col * 512 + kt + gs * 8, dst + c * 8);
    }
}

// ---- kernel 3: FUSED gather + GEMM.  out = relu([Zleft | avg(Z8[nb])] @ WT^T)
// BM=128, N=256, BK=64. 512 thr = 8 waves (2M x 4N), wave = 64x64 = 4x4 frags.
// LDS 160KB: sA dbuf 2x16K + sB dbuf 2x32K + sZ 64K. 1 block/CU.
// Gather interleaved: 4 rows/wave per left K-step; loads issued pre-MFMA,
// consumed post-MFMA; stage(s+1) issued pre-MFMA so barrier's vmcnt(0) is cheap.
__global__ __launch_bounds__(512, 2) void gemm_fused(const u16* __restrict__ A,            // [MTOT][256] bf16
                                                     const unsigned char* __restrict__ Z8, // [MTOT][256] fp8
                                                     const u16* __restrict__ BT,           // [256][512] bf16
                                                     const int* __restrict__ n1,
                                                     const int* __restrict__ n2,
                                                     float* __restrict__ C) {
    __shared__ u16 sA[2][128 * 64];   // 2 x 16 KB
    __shared__ u16 sB[2][256 * 64];   // 2 x 32 KB
    __shared__ u16 sZ[128 * 256];     // 64 KB, XOR-swizzled 16B granules
    const int m0 = blockIdx.x * 128;
    const int t = threadIdx.x;
    const int lane = t & 63;
    const int w = t >> 6;
    const int wr = w >> 2, wc = w & 3;   // 2M x 4N wave grid
    const int l7 = lane & 7;
    const int l15 = lane & 15;

    f32x4 acc[4][4] = {};

    // prologue: stage buf0 (kt=0)
    stage_tileA(A, &sA[0][0], m0, 0, t);
    stage_tileB(BT, &sB[0][0], 0, t);
    __syncthreads();

    // ---- left half: kt = 0..255, with interleaved gather of 4 rows/wave/step
    #pragma unroll
    for (int s = 0; s < 4; ++s) {
        const int cur = s & 1;
        const int kt = s * 64;
        const int rbase = w * 16 + s * 4;

        // 1. load neighbor indices for this step's 4 rows (L2-resident, ~2MB)
        int idxv[4][KNB];
        int pp[4];
        #pragma unroll
        for (int rr = 0; rr < 4; ++rr) {
            int g = m0 + rbase + rr;
            if (g >= MTOT) g = MTOT - 1;
            int p = (g >= NNODE) ? 1 : 0;
            pp[rr] = p;
            const int2* nb2 = (const int2*)((p ? n2 : n1) + (size_t)(g - p * NNODE) * KNB);
            #pragma unroll
            for (int k5 = 0; k5 < 5; ++k5) {
                int2 v = nb2[k5];
                idxv[rr][2 * k5] = v.x;
                idxv[rr][2 * k5 + 1] = v.y;
            }
        }
        // 2. issue gather data loads (oldest vmem -> counted wait won't drain stage)
        uchar4 gdat[4][KNB];
        #pragma unroll
        for (int rr = 0; rr < 4; ++rr) {
            const unsigned char* zb = Z8 + (size_t)pp[rr] * NNODE * 256 + (size_t)lane * 4;
            #pragma unroll
            for (int k = 0; k < KNB; ++k) {
                int idx = idxv[rr][k];
                int safe = (idx > -1) ? idx : 0;
                gdat[rr][k] = *(const uchar4*)(zb + (size_t)safe * 256);
            }
        }
        // 3. stage next K-tile into the other buffer (in flight across MFMA)
        if (s < 3) stage_tileA(A, &sA[cur ^ 1][0], m0, kt + 64, t);
        stage_tileB(BT, &sB[cur ^ 1][0], (s < 3) ? kt + 64 : 256, t);

        // 4. MFMA on buf cur (swizzled reads: granule ^ (row&7) == granule ^ l7)
        #pragma unroll
        for (int kk = 0; kk < 64; kk += 32) {
            int kq = kk + ((lane >> 4) << 3);
            int gx = (kq >> 3) ^ l7;
            bf16x8 af[4], bfr[4];
            #pragma unroll
            for (int i = 0; i < 4; ++i)
                af[i] = *(const bf16x8*)&sA[cur][(wr * 64 + i * 16 + l15) * 64 + gx * 8];
            #pragma unroll
            for (int j = 0; j < 4; ++j)
                bfr[j] = *(const bf16x8*)&sB[cur][(wc * 64 + j * 16 + l15) * 64 + gx * 8];
            #pragma unroll
            for (int i = 0; i < 4; ++i)
                #pragma unroll
                for (int j = 0; j < 4; ++j)
                    acc[i][j] = __builtin_amdgcn_mfma_f32_16x16x32_bf16(af[i], bfr[j], acc[i][j], 0, 0, 0);
        }

        // 5. consume gather loads -> average -> swizzled sZ write
        #pragma unroll
        for (int rr = 0; rr < 4; ++rr) {
            float a0 = 0.f, a1 = 0.f, a2 = 0.f, a3 = 0.f;
            int cnt = 0;
            #pragma unroll
            for (int k = 0; k < KNB; ++k) {
                int valid = (idxv[rr][k] > -1);
                cnt += valid;
                float mm = (float)valid;
                uchar4 v = gdat[rr][k];
                a0 += mm * f8tof(v.x); a1 += mm * f8tof(v.y);
                a2 += mm * f8tof(v.z); a3 += mm * f8tof(v.w);
            }
            float sc = 1.0f / (float)(cnt > 0 ? cnt : 1);
            int r = rbase + rr;
            int gp = (lane >> 1) ^ (r & 7);     // swizzled 16B granule
            ushort4 o;
            o.x = f2bf(a0 * sc); o.y = f2bf(a1 * sc);
            o.z = f2bf(a2 * sc); o.w = f2bf(a3 * sc);
            *(ushort4*)&sZ[r * 256 + gp * 8 + (lane & 1) * 4] = o;
        }
        __syncthreads();
    }

    // ---- right half: kt = 256..511, A-frags from sZ (all gathered), B staged dbuf
    #pragma unroll
    for (int s = 4; s < 8; ++s) {
        const int cur = s & 1;
        const int kt = s * 64;
        if (s < 7) stage_tileB(BT, &sB[cur ^ 1][0], kt + 64, t);
        #pragma unroll
        for (int kk = 0; kk < 64; kk += 32) {
            int kq = kk + ((lane >> 4) << 3);
            int gx = (kq >> 3) ^ l7;
            int gzx = (((kt - 256) + kq) >> 3) ^ l7;   // sZ granule (of 32 per row)
            bf16x8 af[4], bfr[4];
            #pragma unroll
            for (int i = 0; i < 4; ++i)
                af[i] = *(const bf16x8*)&sZ[(wr * 64 + i * 16 + l15) * 256 + gzx * 8];
            #pragma unroll
            for (int j = 0; j < 4; ++j)
                bfr[j] = *(const bf16x8*)&sB[cur][(wc * 64 + j * 16 + l15) * 64 + gx * 8];
            #pragma unroll
            for (int i = 0; i < 4; ++i)
                #pragma unroll
                for (int j = 0; j < 4; ++j)
                    acc[i][j] = __builtin_amdgcn_mfma_f32_16x16x32_bf16(af[i], bfr[j], acc[i][j], 0, 0, 0);
        }
        if (s < 7) __syncthreads();
    }

    // ---- epilogue: relu + store (C/D layout: col = lane&15, row = (lane>>4)*4 + q)
    #pragma unroll
    for (int i = 0; i < 4; ++i) {
        int rbase = m0 + wr * 64 + i * 16 + ((lane >> 4) << 2);
        #pragma unroll
        for (int j = 0; j < 4; ++j) {
            int col = wc * 64 + j * 16 + l15;
            #pragma unroll
            for (int q = 0; q < 4; ++q) {
                int row = rbase + q;
                if (row < MTOT) C[(size_t)row * NF + col] = fmaxf(acc[i][j][q], 0.f);
            }
        }
    }
}

extern "C" void kernel_launch(void* const* d_in, const int* in_sizes, int n_in,
                              void* d_out, int out_size, void* d_ws, size_t ws_size,
                              hipStream_t stream) {
    const float* Z1  = (const float*)d_in[0];
    const float* Z2  = (const float*)d_in[1];
    const float* Wr  = (const float*)d_in[2];
    const float* Wnr = (const float*)d_in[3];
    const int*   n1  = (const int*)d_in[4];
    const int*   n2  = (const int*)d_in[5];
    float* out = (float*)d_out;

    u16* WT    = (u16*)d_ws;                            // [256][512]    0.26 MB
    u16* Zleft = WT + 256 * 512;                        // [100000][256] 51.2 MB
    unsigned char* Z8 = (unsigned char*)(Zleft + (size_t)MTOT * 256);  // 25.6 MB
    // total ws use: 77.1 MB

    cast_w<<<512, 256, 0, stream>>>(Wr, Wnr, WT);
    cast_z<<<12500, 256, 0, stream>>>(Z1, Z2, Zleft, Z8);
    gemm_fused<<<782, 512, 0, stream>>>(Zleft, Z8, WT, n1, n2, out);
}

// Round 6
// 131.413 us; speedup vs baseline: 1.1293x; 1.0699x over previous
//
#include <hip/hip_runtime.h>
#include <hip/hip_bf16.h>
#include <hip/hip_fp8.h>

#define NNODE 50000
#define MTOT  100000   // 2*NNODE rows
#define NF    256
#define KNB   10

typedef unsigned short u16;
typedef float f32x4 __attribute__((ext_vector_type(4)));
typedef float f32x2 __attribute__((ext_vector_type(2)));
typedef short bf16x8 __attribute__((ext_vector_type(8)));

__device__ __forceinline__ u16 f2bf(float f) {
    unsigned u = __builtin_bit_cast(unsigned, f);
    unsigned r = (u + 0x7fffu + ((u >> 16) & 1u)) >> 16;
    return (u16)r;
}
__device__ __forceinline__ unsigned char f2f8(float f) {
    return (unsigned char)__hip_fp8_e4m3(f).__x;
}
__device__ __forceinline__ float f8tof(unsigned char b) {
    __hip_fp8_e4m3 h;
    h.__x = (__hip_fp8_storage_t)b;
    return (float)h;
}
template <int WORD>
__device__ __forceinline__ f32x2 cvt2_fp8(unsigned v) {
#if __has_builtin(__builtin_amdgcn_cvt_pk_f32_fp8)
    auto c = __builtin_amdgcn_cvt_pk_f32_fp8((int)v, WORD);   // WORD is a literal
    f32x2 r; r.x = c[0]; r.y = c[1];
    return r;
#else
    unsigned s = WORD ? (v >> 16) : v;
    f32x2 r;
    r.x = f8tof((unsigned char)(s & 0xff));
    r.y = f8tof((unsigned char)((s >> 8) & 0xff));
    return r;
#endif
}
__device__ __forceinline__ void gload_lds16(const void* g, void* l) {
    __builtin_amdgcn_global_load_lds(
        (const __attribute__((address_space(1))) unsigned int*)g,
        (__attribute__((address_space(3))) unsigned int*)l, 16, 0, 0);
}

// ---- kernel 1: merged cast.  blocks [0,12500): Z -> bf16 Zleft + fp8 Z8.
//                blocks [12500,13012): W^T cast.
__global__ __launch_bounds__(256) void cast_all(const float* __restrict__ Z1,
                                                const float* __restrict__ Z2,
                                                const float* __restrict__ Wr,
                                                const float* __restrict__ Wnr,
                                                u16* __restrict__ Zleft,
                                                unsigned char* __restrict__ Z8,
                                                u16* __restrict__ WT) {
    int b = blockIdx.x;
    if (b < 12500) {
        unsigned id = b * 256 + threadIdx.x;  // 3,200,000 total (8 elems each)
        int m = id >> 5;
        int d = (id & 31) << 3;
        const float* src = (m < NNODE) ? (Z1 + (size_t)m * 256 + d)
                                       : (Z2 + (size_t)(m - NNODE) * 256 + d);
        float4 a = *(const float4*)src;
        float4 bb = *(const float4*)(src + 4);
        uint4 o;
        o.x = (unsigned)f2bf(a.x) | ((unsigned)f2bf(a.y) << 16);
        o.y = (unsigned)f2bf(a.z) | ((unsigned)f2bf(a.w) << 16);
        o.z = (unsigned)f2bf(bb.x) | ((unsigned)f2bf(bb.y) << 16);
        o.w = (unsigned)f2bf(bb.z) | ((unsigned)f2bf(bb.w) << 16);
        *(uint4*)(Zleft + (size_t)m * 256 + d) = o;
        uint2 o8;
        o8.x = (unsigned)f2f8(a.x) | ((unsigned)f2f8(a.y) << 8) |
               ((unsigned)f2f8(a.z) << 16) | ((unsigned)f2f8(a.w) << 24);
        o8.y = (unsigned)f2f8(bb.x) | ((unsigned)f2f8(bb.y) << 8) |
               ((unsigned)f2f8(bb.z) << 16) | ((unsigned)f2f8(bb.w) << 24);
        *(uint2*)(Z8 + (size_t)m * 256 + d) = o8;
    } else {
        int id = (b - 12500) * 256 + threadIdx.x;   // 131072 total
        int n = id >> 9;
        int k = id & 511;
        float v = (k < 256) ? Wr[(size_t)k * 256 + n] : Wnr[(size_t)(k - 256) * 256 + n];
        WT[(size_t)n * 512 + k] = f2bf(v);
    }
}

// ---- staging helpers: linear LDS dest + INVERSE-swizzled global source
__device__ __forceinline__ void stage_tileA(const u16* __restrict__ A, u16* dst,
                                            int m0, int kt, int t) {
    #pragma unroll
    for (int rp = 0; rp < 2; ++rp) {           // 1024 granules of 16B, 2/thread
        int c = rp * 512 + t;
        int row = c >> 3, gd = c & 7;
        int gs = gd ^ (row & 7);
        int grow = m0 + row;
        if (grow >= MTOT) grow = MTOT - 1;
        gload_lds16(A + (size_t)grow * 256 + kt + gs * 8, dst + c * 8);
    }
}
__device__ __forceinline__ void stage_tileB(const u16* __restrict__ BT, u16* dst,
                                            int kt, int t) {
    #pragma unroll
    for (int rp = 0; rp < 4; ++rp) {           // 2048 granules of 16B, 4/thread
        int c = rp * 512 + t;
        int col = c >> 3, gd = c & 7;
        int gs = gd ^ (col & 7);
        gload_lds16(BT + (size_t)col * 512 + kt + gs * 8, dst + c * 8);
    }
}

// ---- gather: issue 40 loads for group GRP (4 rows x 10 nb), addresses via SGPR idx
template <int GRPX>
__device__ __forceinline__ void gather_issue(const unsigned char* __restrict__ Z8,
                                             const int (&vidx)[3], int m0, int w,
                                             int vo, uchar4 (&buf)[40]) {
    constexpr int GRP = (GRPX > 3) ? 3 : GRPX;   // clamp for dead instantiations
    #pragma unroll
    for (int rr = 0; rr < 4; ++rr) {
        int g = m0 + (w << 4) + GRP * 4 + rr;
        if (g >= MTOT) g = MTOT - 1;
        g = __builtin_amdgcn_readfirstlane(g);
        const unsigned char* rb = Z8 + (size_t)(g >= NNODE) * ((size_t)NNODE * 256);
        #pragma unroll
        for (int k = 0; k < KNB; ++k) {
            int f = (GRP * 4 + rr) * 10 + k;     // compile-time after unroll
            int ix = __builtin_amdgcn_readlane(vidx[f >> 6], f & 63);
            int safe = (ix > -1) ? ix : 0;
            buf[rr * 10 + k] = *(const uchar4*)(rb + (size_t)safe * 256 + vo);
        }
    }
}

// ---- consume: average group GRP -> swizzled sZ write
template <int GRPX>
__device__ __forceinline__ void consume_avg(const int (&vidx)[3], int w, int lane,
                                            const uchar4 (&buf)[40], u16* sZ) {
    constexpr int GRP = (GRPX > 3) ? 3 : GRPX;
    #pragma unroll
    for (int rr = 0; rr < 4; ++rr) {
        f32x2 a01 = {0.f, 0.f}, a23 = {0.f, 0.f};
        int cnt = 0;
        #pragma unroll
        for (int k = 0; k < KNB; ++k) {
            int f = (GRP * 4 + rr) * 10 + k;
            int ix = __builtin_amdgcn_readlane(vidx[f >> 6], f & 63);
            int valid = (ix > -1);
            cnt += valid;
            unsigned raw = __builtin_bit_cast(unsigned, buf[rr * 10 + k]);
            raw = valid ? raw : 0u;
            a01 += cvt2_fp8<0>(raw);
            a23 += cvt2_fp8<1>(raw);
        }
        float sc = 1.0f / (float)(cnt > 0 ? cnt : 1);
        int r = (w << 4) + GRP * 4 + rr;          // local row 0..127
        int gp = (lane >> 1) ^ (r & 7);
        ushort4 o;
        o.x = f2bf(a01.x * sc); o.y = f2bf(a01.y * sc);
        o.z = f2bf(a23.x * sc); o.w = f2bf(a23.y * sc);
        *(ushort4*)&sZ[r * 256 + gp * 8 + (lane & 1) * 4] = o;
    }
}

__device__ __forceinline__ void mfma_left(const u16* sAc, const u16* sBc, int lane,
                                          int wr, int wc, f32x4 (&acc)[4][4]) {
    const int l7 = lane & 7, l15 = lane & 15;
    #pragma unroll
    for (int kk = 0; kk < 64; kk += 32) {
        int kq = kk + ((lane >> 4) << 3);
        int gx = (kq >> 3) ^ l7;
        bf16x8 af[4], bfr[4];
        #pragma unroll
        for (int i = 0; i < 4; ++i)
            af[i] = *(const bf16x8*)&sAc[(wr * 64 + i * 16 + l15) * 64 + gx * 8];
        #pragma unroll
        for (int j = 0; j < 4; ++j)
            bfr[j] = *(const bf16x8*)&sBc[(wc * 64 + j * 16 + l15) * 64 + gx * 8];
        #pragma unroll
        for (int i = 0; i < 4; ++i)
            #pragma unroll
            for (int j = 0; j < 4; ++j)
                acc[i][j] = __builtin_amdgcn_mfma_f32_16x16x32_bf16(af[i], bfr[j], acc[i][j], 0, 0, 0);
    }
}
__device__ __forceinline__ void mfma_right(const u16* sZc, const u16* sBc, int kt0, int lane,
                                           int wr, int wc, f32x4 (&acc)[4][4]) {
    const int l7 = lane & 7, l15 = lane & 15;
    #pragma unroll
    for (int kk = 0; kk < 64; kk += 32) {
        int kq = kk + ((lane >> 4) << 3);
        int gx = (kq >> 3) ^ l7;
        int gzx = ((kt0 + kq) >> 3) ^ l7;
        bf16x8 af[4], bfr[4];
        #pragma unroll
        for (int i = 0; i < 4; ++i)
            af[i] = *(const bf16x8*)&sZc[(wr * 64 + i * 16 + l15) * 256 + gzx * 8];
        #pragma unroll
        for (int j = 0; j < 4; ++j)
            bfr[j] = *(const bf16x8*)&sBc[(wc * 64 + j * 16 + l15) * 64 + gx * 8];
        #pragma unroll
        for (int i = 0; i < 4; ++i)
            #pragma unroll
            for (int j = 0; j < 4; ++j)
                acc[i][j] = __builtin_amdgcn_mfma_f32_16x16x32_bf16(af[i], bfr[j], acc[i][j], 0, 0, 0);
    }
}

// ---- kernel 2: FUSED gather + GEMM with counted-vmcnt raw-barrier pipeline.
// BM=128, N=256, BK=64. 512 thr = 8 waves (2M x 4N). LDS 160KB, 1 block/CU.
__global__ __launch_bounds__(512, 2) void gemm_fused(const u16* __restrict__ A,            // [MTOT][256] bf16
                                                     const unsigned char* __restrict__ Z8, // [MTOT][256] fp8
                                                     const u16* __restrict__ BT,           // [256][512] bf16
                                                     const int* __restrict__ n1,
                                                     const int* __restrict__ n2,
                                                     float* __restrict__ C) {
    __shared__ u16 sA[2][128 * 64];   // 2 x 16 KB
    __shared__ u16 sB[2][256 * 64];   // 2 x 32 KB
    __shared__ u16 sZ[128 * 256];     // 64 KB, XOR-swizzled 16B granules
    const int m0 = blockIdx.x * 128;
    const int t = threadIdx.x;
    const int lane = t & 63;
    const int w = t >> 6;
    const int wr = w >> 2, wc = w & 3;
    const int vo = lane * 4;

    f32x4 acc[4][4] = {};
    uchar4 gbuf[2][40];

    // ---- prologue: lane-distributed index load (wave's 16 rows x 10 = 160 ints)
    int vidx[3];
    #pragma unroll
    for (int j = 0; j < 3; ++j) {
        int f = lane + j * 64;
        if (f > 159) f = 159;
        int rl = f / 10;
        int kk2 = f - rl * 10;
        int g = m0 + (w << 4) + rl;
        if (g >= MTOT) g = MTOT - 1;
        int p = (g >= NNODE);
        vidx[j] = *((p ? n2 : n1) + (size_t)(g - p * NNODE) * KNB + kk2);
    }
    stage_tileA(A, &sA[0][0], m0, 0, t);
    stage_tileB(BT, &sB[0][0], 0, t);
    gather_issue<0>(Z8, vidx, m0, w, vo, gbuf[0]);

#define LEFT_STEP(S)                                                        \
    do {                                                                    \
        if ((S) < 3) {                                                      \
            gather_issue<(S) + 1>(Z8, vidx, m0, w, vo, gbuf[((S) + 1) & 1]);\
            stage_tileA(A, &sA[((S) + 1) & 1][0], m0, ((S) + 1) * 64, t);   \
            stage_tileB(BT, &sB[((S) + 1) & 1][0], ((S) + 1) * 64, t);      \
            asm volatile("s_waitcnt vmcnt(46)" ::: "memory");               \
        } else {                                                            \
            stage_tileB(BT, &sB[((S) + 1) & 1][0], 256, t);                 \
            asm volatile("s_waitcnt vmcnt(4)" ::: "memory");                \
        }                                                                   \
        __builtin_amdgcn_s_barrier();                                       \
        __builtin_amdgcn_s_setprio(1);                                      \
        mfma_left(&sA[(S) & 1][0], &sB[(S) & 1][0], lane, wr, wc, acc);     \
        __builtin_amdgcn_s_setprio(0);                                      \
        consume_avg<(S)>(vidx, w, lane, gbuf[(S) & 1], &sZ[0]);             \
        asm volatile("s_waitcnt lgkmcnt(0)" ::: "memory");                  \
        __builtin_amdgcn_s_barrier();                                       \
    } while (0)

    LEFT_STEP(0);
    LEFT_STEP(1);
    LEFT_STEP(2);
    LEFT_STEP(3);
#undef LEFT_STEP

#define RIGHT_STEP(S)                                                       \
    do {                                                                    \
        if ((S) < 7) {                                                      \
            stage_tileB(BT, &sB[((S) + 1) & 1][0], ((S) + 1) * 64, t);      \
            asm volatile("s_waitcnt vmcnt(4)" ::: "memory");                \
        } else {                                                            \
            asm volatile("s_waitcnt vmcnt(0)" ::: "memory");                \
        }                                                                   \
        __builtin_amdgcn_s_barrier();                                       \
        __builtin_amdgcn_s_setprio(1);                                      \
        mfma_right(&sZ[0], &sB[(S) & 1][0], ((S) - 4) * 64, lane, wr, wc, acc); \
        __builtin_amdgcn_s_setprio(0);                                      \
        if ((S) < 7) __builtin_amdgcn_s_barrier();                          \
    } while (0)

    RIGHT_STEP(4);
    RIGHT_STEP(5);
    RIGHT_STEP(6);
    RIGHT_STEP(7);
#undef RIGHT_STEP

    // ---- epilogue: relu + store (C/D layout: col = lane&15, row = (lane>>4)*4 + q)
    const int l15 = lane & 15;
    #pragma unroll
    for (int i = 0; i < 4; ++i) {
        int rbase = m0 + wr * 64 + i * 16 + ((lane >> 4) << 2);
        #pragma unroll
        for (int j = 0; j < 4; ++j) {
            int col = wc * 64 + j * 16 + l15;
            #pragma unroll
            for (int q = 0; q < 4; ++q) {
                int row = rbase + q;
                if (row < MTOT) C[(size_t)row * NF + col] = fmaxf(acc[i][j][q], 0.f);
            }
        }
    }
}

extern "C" void kernel_launch(void* const* d_in, const int* in_sizes, int n_in,
                              void* d_out, int out_size, void* d_ws, size_t ws_size,
                              hipStream_t stream) {
    const float* Z1  = (const float*)d_in[0];
    const float* Z2  = (const float*)d_in[1];
    const float* Wr  = (const float*)d_in[2];
    const float* Wnr = (const float*)d_in[3];
    const int*   n1  = (const int*)d_in[4];
    const int*   n2  = (const int*)d_in[5];
    float* out = (float*)d_out;

    u16* WT    = (u16*)d_ws;                            // [256][512]    0.26 MB
    u16* Zleft = WT + 256 * 512;                        // [100000][256] 51.2 MB
    unsigned char* Z8 = (unsigned char*)(Zleft + (size_t)MTOT * 256);  // 25.6 MB
    // total ws use: 77.1 MB

    cast_all<<<13012, 256, 0, stream>>>(Z1, Z2, Wr, Wnr, Zleft, Z8, WT);
    gemm_fused<<<782, 512, 0, stream>>>(Zleft, Z8, WT, n1, n2, out);
}

// Round 7
// 121.408 us; speedup vs baseline: 1.2224x; 1.0824x over previous
//
#include <hip/hip_runtime.h>
#include <hip/hip_bf16.h>
#include <hip/hip_fp8.h>

#define NNODE 50000
#define MTOT  100000   // 2*NNODE rows
#define NF    256
#define KNB   10

typedef unsigned short u16;
typedef float f32x4 __attribute__((ext_vector_type(4)));
typedef float f32x2 __attribute__((ext_vector_type(2)));
typedef short bf16x8 __attribute__((ext_vector_type(8)));

__device__ __forceinline__ u16 f2bf(float f) {
    unsigned u = __builtin_bit_cast(unsigned, f);
    unsigned r = (u + 0x7fffu + ((u >> 16) & 1u)) >> 16;
    return (u16)r;
}
__device__ __forceinline__ unsigned char f2f8(float f) {
    return (unsigned char)__hip_fp8_e4m3(f).__x;
}
__device__ __forceinline__ float f8tof(unsigned char b) {
    __hip_fp8_e4m3 h;
    h.__x = (__hip_fp8_storage_t)b;
    return (float)h;
}
template <int WORD>
__device__ __forceinline__ f32x2 cvt2_fp8(unsigned v) {
#if __has_builtin(__builtin_amdgcn_cvt_pk_f32_fp8)
    auto c = __builtin_amdgcn_cvt_pk_f32_fp8((int)v, WORD);   // WORD literal
    f32x2 r; r.x = c[0]; r.y = c[1];
    return r;
#else
    unsigned s = WORD ? (v >> 16) : v;
    f32x2 r;
    r.x = f8tof((unsigned char)(s & 0xff));
    r.y = f8tof((unsigned char)((s >> 8) & 0xff));
    return r;
#endif
}
__device__ __forceinline__ unsigned pack_bf16(float lo, float hi) {
    unsigned r;
    asm("v_cvt_pk_bf16_f32 %0, %1, %2" : "=v"(r) : "v"(lo), "v"(hi));
    return r;
}
__device__ __forceinline__ void gload_lds16(const void* g, void* l) {
    __builtin_amdgcn_global_load_lds(
        (const __attribute__((address_space(1))) unsigned int*)g,
        (__attribute__((address_space(3))) unsigned int*)l, 16, 0, 0);
}

// ---- kernel 1: merged cast.  blocks [0,12500): Z -> bf16 Zleft + fp8 Z8.
//                blocks [12500,13012): W^T cast.
__global__ __launch_bounds__(256) void cast_all(const float* __restrict__ Z1,
                                                const float* __restrict__ Z2,
                                                const float* __restrict__ Wr,
                                                const float* __restrict__ Wnr,
                                                u16* __restrict__ Zleft,
                                                unsigned char* __restrict__ Z8,
                                                u16* __restrict__ WT) {
    int b = blockIdx.x;
    if (b < 12500) {
        unsigned id = b * 256 + threadIdx.x;  // 3,200,000 total (8 elems each)
        int m = id >> 5;
        int d = (id & 31) << 3;
        const float* src = (m < NNODE) ? (Z1 + (size_t)m * 256 + d)
                                       : (Z2 + (size_t)(m - NNODE) * 256 + d);
        float4 a = *(const float4*)src;
        float4 bb = *(const float4*)(src + 4);
        uint4 o;
        o.x = (unsigned)f2bf(a.x) | ((unsigned)f2bf(a.y) << 16);
        o.y = (unsigned)f2bf(a.z) | ((unsigned)f2bf(a.w) << 16);
        o.z = (unsigned)f2bf(bb.x) | ((unsigned)f2bf(bb.y) << 16);
        o.w = (unsigned)f2bf(bb.z) | ((unsigned)f2bf(bb.w) << 16);
        *(uint4*)(Zleft + (size_t)m * 256 + d) = o;
        uint2 o8;
        o8.x = (unsigned)f2f8(a.x) | ((unsigned)f2f8(a.y) << 8) |
               ((unsigned)f2f8(a.z) << 16) | ((unsigned)f2f8(a.w) << 24);
        o8.y = (unsigned)f2f8(bb.x) | ((unsigned)f2f8(bb.y) << 8) |
               ((unsigned)f2f8(bb.z) << 16) | ((unsigned)f2f8(bb.w) << 24);
        *(uint2*)(Z8 + (size_t)m * 256 + d) = o8;
    } else {
        int id = (b - 12500) * 256 + threadIdx.x;   // 131072 total
        int n = id >> 9;
        int k = id & 511;
        float v = (k < 256) ? Wr[(size_t)k * 256 + n] : Wnr[(size_t)(k - 256) * 256 + n];
        WT[(size_t)n * 512 + k] = f2bf(v);
    }
}

// ---- staging helpers: linear LDS dest + INVERSE-swizzled global source
__device__ __forceinline__ void stage_tileA(const u16* __restrict__ A, u16* dst,
                                            int m0, int kt, int t) {
    #pragma unroll
    for (int rp = 0; rp < 2; ++rp) {           // 1024 granules of 16B, 2/thread
        int c = rp * 512 + t;
        int row = c >> 3, gd = c & 7;
        int gs = gd ^ (row & 7);
        int grow = m0 + row;
        if (grow >= MTOT) grow = MTOT - 1;
        gload_lds16(A + (size_t)grow * 256 + kt + gs * 8, dst + c * 8);
    }
}
__device__ __forceinline__ void stage_tileB(const u16* __restrict__ BT, u16* dst,
                                            int kt, int t) {
    #pragma unroll
    for (int rp = 0; rp < 4; ++rp) {           // 2048 granules of 16B, 4/thread
        int c = rp * 512 + t;
        int col = c >> 3, gd = c & 7;
        int gs = gd ^ (col & 7);
        gload_lds16(BT + (size_t)col * 512 + kt + gs * 8, dst + c * 8);
    }
}

// ---- gather step S: 10 uint4 loads; lane group (lane>>4) owns row rbase+group,
// lane covers 16 fp8 cols starting (lane&15)*16. One instr = same k, 4 rows.
template <int S>
__device__ __forceinline__ void gather_issue2(const unsigned char* __restrict__ Z8,
                                              const int (&idxv)[4][KNB],
                                              const unsigned (&rowoff)[4],
                                              uint4 (&gb)[KNB]) {
    #pragma unroll
    for (int k = 0; k < KNB; ++k) {
        int ix = idxv[S][k];
        unsigned off = rowoff[S] + (unsigned)((ix > -1) ? ix : 0) * 256u;
        gb[k] = *(const uint4*)(Z8 + (size_t)off);
    }
}

// ---- consume step S: average 10 neighbors (16 cols/lane) -> swizzled sZ write
template <int S>
__device__ __forceinline__ void consume2(const int (&idxv)[4][KNB], int w, int lane,
                                         const uint4 (&gb)[KNB], u16* sZ) {
    f32x2 ac[8];
    #pragma unroll
    for (int j = 0; j < 8; ++j) ac[j] = f32x2{0.f, 0.f};
    int cnt = 0;
    #pragma unroll
    for (int k = 0; k < KNB; ++k) {
        int valid = (idxv[S][k] > -1);
        cnt += valid;
        float mm = (float)valid;
        f32x2 m2 = {mm, mm};
        uint4 v = gb[k];
        ac[0] += m2 * cvt2_fp8<0>(v.x); ac[1] += m2 * cvt2_fp8<1>(v.x);
        ac[2] += m2 * cvt2_fp8<0>(v.y); ac[3] += m2 * cvt2_fp8<1>(v.y);
        ac[4] += m2 * cvt2_fp8<0>(v.z); ac[5] += m2 * cvt2_fp8<1>(v.z);
        ac[6] += m2 * cvt2_fp8<0>(v.w); ac[7] += m2 * cvt2_fp8<1>(v.w);
    }
    float sc = 1.0f / (float)(cnt > 0 ? cnt : 1);
    unsigned pw[8];
    #pragma unroll
    for (int j = 0; j < 8; ++j)
        pw[j] = pack_bf16(ac[j].x * sc, ac[j].y * sc);
    int r = (w << 4) + S * 4 + (lane >> 4);          // local row 0..127
    int g0 = 2 * (lane & 15);                        // 16B granule of 32 per row
    unsigned b0 = r * 512 + (((g0)     ^ (r & 7)) << 4);
    unsigned b1 = r * 512 + (((g0 + 1) ^ (r & 7)) << 4);
    *(uint4*)((char*)sZ + b0) = uint4{pw[0], pw[1], pw[2], pw[3]};
    *(uint4*)((char*)sZ + b1) = uint4{pw[4], pw[5], pw[6], pw[7]};
}

__device__ __forceinline__ void mfma_left(const u16* sAc, const u16* sBc, int lane,
                                          int wr, int wc, f32x4 (&acc)[4][4]) {
    const int l7 = lane & 7, l15 = lane & 15;
    #pragma unroll
    for (int kk = 0; kk < 64; kk += 32) {
        int kq = kk + ((lane >> 4) << 3);
        int gx = (kq >> 3) ^ l7;
        bf16x8 af[4], bfr[4];
        #pragma unroll
        for (int i = 0; i < 4; ++i)
            af[i] = *(const bf16x8*)&sAc[(wr * 64 + i * 16 + l15) * 64 + gx * 8];
        #pragma unroll
        for (int j = 0; j < 4; ++j)
            bfr[j] = *(const bf16x8*)&sBc[(wc * 64 + j * 16 + l15) * 64 + gx * 8];
        #pragma unroll
        for (int i = 0; i < 4; ++i)
            #pragma unroll
            for (int j = 0; j < 4; ++j)
                acc[i][j] = __builtin_amdgcn_mfma_f32_16x16x32_bf16(af[i], bfr[j], acc[i][j], 0, 0, 0);
    }
}
__device__ __forceinline__ void mfma_right(const u16* sZc, const u16* sBc, int kt0, int lane,
                                           int wr, int wc, f32x4 (&acc)[4][4]) {
    const int l7 = lane & 7, l15 = lane & 15;
    #pragma unroll
    for (int kk = 0; kk < 64; kk += 32) {
        int kq = kk + ((lane >> 4) << 3);
        int gx = (kq >> 3) ^ l7;
        int gzx = ((kt0 + kq) >> 3) ^ l7;
        bf16x8 af[4], bfr[4];
        #pragma unroll
        for (int i = 0; i < 4; ++i)
            af[i] = *(const bf16x8*)&sZc[(wr * 64 + i * 16 + l15) * 256 + gzx * 8];
        #pragma unroll
        for (int j = 0; j < 4; ++j)
            bfr[j] = *(const bf16x8*)&sBc[(wc * 64 + j * 16 + l15) * 64 + gx * 8];
        #pragma unroll
        for (int i = 0; i < 4; ++i)
            #pragma unroll
            for (int j = 0; j < 4; ++j)
                acc[i][j] = __builtin_amdgcn_mfma_f32_16x16x32_bf16(af[i], bfr[j], acc[i][j], 0, 0, 0);
    }
}

// ---- kernel 2: FUSED gather + GEMM, counted-vmcnt pipeline, <=32 vmem in flight.
// BM=128, N=256, BK=64. 512 thr = 8 waves (2M x 4N). LDS 160KB, 1 block/CU.
__global__ __launch_bounds__(512, 2) void gemm_fused(const u16* __restrict__ A,            // [MTOT][256] bf16
                                                     const unsigned char* __restrict__ Z8, // [MTOT][256] fp8
                                                     const u16* __restrict__ BT,           // [256][512] bf16
                                                     const int* __restrict__ n1,
                                                     const int* __restrict__ n2,
                                                     float* __restrict__ C) {
    __shared__ u16 sA[2][128 * 64];   // 2 x 16 KB
    __shared__ u16 sB[2][256 * 64];   // 2 x 32 KB
    __shared__ u16 sZ[128 * 256];     // 64 KB, XOR-swizzled 16B granules
    const int m0 = blockIdx.x * 128;
    const int t = threadIdx.x;
    const int lane = t & 63;
    const int w = t >> 6;
    const int wr = w >> 2, wc = w & 3;

    f32x4 acc[4][4] = {};
    uint4 gbuf[2][KNB];

    // ---- prologue: stage tile 0, load ALL 40 neighbor indices for this lane's rows
    stage_tileA(A, &sA[0][0], m0, 0, t);
    stage_tileB(BT, &sB[0][0], 0, t);

    int idxv[4][KNB];
    unsigned rowoff[4];
    #pragma unroll
    for (int s = 0; s < 4; ++s) {
        int g = m0 + (w << 4) + s * 4 + (lane >> 4);
        if (g >= MTOT) g = MTOT - 1;
        int p = (g >= NNODE);
        const int* nb = (p ? n2 : n1) + (size_t)(g - p * NNODE) * KNB;
        #pragma unroll
        for (int q = 0; q < 5; ++q) {
            int2 v = *(const int2*)(nb + 2 * q);
            idxv[s][2 * q] = v.x;
            idxv[s][2 * q + 1] = v.y;
        }
        rowoff[s] = (unsigned)p * (unsigned)(NNODE * 256) + (unsigned)((lane & 15) << 4);
    }
    gather_issue2<0>(Z8, idxv, rowoff, gbuf[0]);

#define LEFT_STEP(S)                                                        \
    do {                                                                    \
        if ((S) < 3) {                                                      \
            stage_tileA(A, &sA[((S) + 1) & 1][0], m0, ((S) + 1) * 64, t);   \
            stage_tileB(BT, &sB[((S) + 1) & 1][0], ((S) + 1) * 64, t);      \
            gather_issue2<((S) < 3 ? (S) + 1 : 3)>(Z8, idxv, rowoff,        \
                                                   gbuf[((S) + 1) & 1]);    \
            asm volatile("s_waitcnt vmcnt(16)" ::: "memory");               \
        } else {                                                            \
            stage_tileB(BT, &sB[((S) + 1) & 1][0], 256, t);                 \
            asm volatile("s_waitcnt vmcnt(4)" ::: "memory");                \
        }                                                                   \
        __builtin_amdgcn_s_barrier();                                       \
        __builtin_amdgcn_s_setprio(1);                                      \
        mfma_left(&sA[(S) & 1][0], &sB[(S) & 1][0], lane, wr, wc, acc);     \
        __builtin_amdgcn_s_setprio(0);                                      \
        consume2<(S)>(idxv, w, lane, gbuf[(S) & 1], &sZ[0]);                \
        if ((S) == 3) asm volatile("s_waitcnt lgkmcnt(0)" ::: "memory");    \
        __builtin_amdgcn_s_barrier();                                       \
    } while (0)

    LEFT_STEP(0);
    LEFT_STEP(1);
    LEFT_STEP(2);
    LEFT_STEP(3);
#undef LEFT_STEP

#define RIGHT_STEP(S)                                                       \
    do {                                                                    \
        if ((S) < 7) {                                                      \
            stage_tileB(BT, &sB[((S) + 1) & 1][0], ((S) + 1) * 64, t);      \
            asm volatile("s_waitcnt vmcnt(4)" ::: "memory");                \
        } else {                                                            \
            asm volatile("s_waitcnt vmcnt(0)" ::: "memory");                \
        }                                                                   \
        __builtin_amdgcn_s_barrier();                                       \
        __builtin_amdgcn_s_setprio(1);                                      \
        mfma_right(&sZ[0], &sB[(S) & 1][0], ((S) - 4) * 64, lane, wr, wc, acc); \
        __builtin_amdgcn_s_setprio(0);                                      \
        if ((S) < 7) __builtin_amdgcn_s_barrier();                          \
    } while (0)

    RIGHT_STEP(4);
    RIGHT_STEP(5);
    RIGHT_STEP(6);
    RIGHT_STEP(7);
#undef RIGHT_STEP

    // ---- epilogue: relu + store (C/D layout: col = lane&15, row = (lane>>4)*4 + q)
    const int l15 = lane & 15;
    #pragma unroll
    for (int i = 0; i < 4; ++i) {
        int rbase = m0 + wr * 64 + i * 16 + ((lane >> 4) << 2);
        #pragma unroll
        for (int j = 0; j < 4; ++j) {
            int col = wc * 64 + j * 16 + l15;
            #pragma unroll
            for (int q = 0; q < 4; ++q) {
                int row = rbase + q;
                if (row < MTOT) C[(size_t)row * NF + col] = fmaxf(acc[i][j][q], 0.f);
            }
        }
    }
}

extern "C" void kernel_launch(void* const* d_in, const int* in_sizes, int n_in,
                              void* d_out, int out_size, void* d_ws, size_t ws_size,
                              hipStream_t stream) {
    const float* Z1  = (const float*)d_in[0];
    const float* Z2  = (const float*)d_in[1];
    const float* Wr  = (const float*)d_in[2];
    const float* Wnr = (const float*)d_in[3];
    const int*   n1  = (const int*)d_in[4];
    const int*   n2  = (const int*)d_in[5];
    float* out = (float*)d_out;

    u16* WT    = (u16*)d_ws;                            // [256][512]    0.26 MB
    u16* Zleft = WT + 256 * 512;                        // [100000][256] 51.2 MB
    unsigned char* Z8 = (unsigned char*)(Zleft + (size_t)MTOT * 256);  // 25.6 MB
    // total ws use: 77.1 MB

    cast_all<<<13012, 256, 0, stream>>>(Z1, Z2, Wr, Wnr, Zleft, Z8, WT);
    gemm_fused<<<782, 512, 0, stream>>>(Zleft, Z8, WT, n1, n2, out);
}